// Round 1
// baseline (3615.401 us; speedup 1.0000x reference)
//
#include <hip/hip_runtime.h>
#include <math.h>

// DRL4TSP decode: B=512 batch, F=2 feat, N=128 nodes, H=256 hidden, 128 steps.
// Design: one workgroup (512 thr) owns 2 batch elements; all 128 steps run
// inside the kernel (batch elements are independent -> no grid sync).
// All (B,H,N) precomputed tensors are algebraically collapsed to per-h
// coefficient vectors (F=2 rank trick); W_ih and Wp_c GEMVs collapse too.
// Remaining per-step work: gh = W_hh*h (768KB), q = Wa_h*h (256KB), and the
// tanh attention/pointer scans (recomputed from coefficients in-register).

#define NB 512
#define NF 2
#define NN 128
#define NH 256
#define NH3 768

// ws layout (floats):
//   0     : Mgi[768] float2   (W_ih·Wdec, 2 cols interleaved)
//   1536  : cgi[768]          (W_ih·bdec + b_ih)
//   2304  : cA[256] float4    (2*A_s0, 2*A_s1, 2*A_d1, va)
//   3328  : a0[256]           (2*(Wa_s·bs + Wa_d·(20*Wd0+bd)))
//   3584  : cP[256] float4    (2*P_s0, 2*P_s1, vp, 0)
//   4608  : pb[256]           (2*(Wp_c·bs + Wp_s·bs))
//   4864  : PC0[256]          (2*Wp_c·Ws0)
//   5120  : PC1[256]          (2*Wp_c·Ws1)
//   5376  : WaH[256*256]      (2*Wa[:,2H:2H+H] packed row-major)
// The factor 2 pre-folds tanh(x)=1-2/(1+exp(2x))'s doubling (exact, x2.0f).

__device__ __forceinline__ float fast_rcp(float x) { return __builtin_amdgcn_rcpf(x); }
__device__ __forceinline__ float sigm(float x) { return fast_rcp(1.0f + __expf(-x)); }
// input y is ALREADY 2*x (coefficients pre-scaled by 2)
__device__ __forceinline__ float tanh_e(float y) { return 1.0f - 2.0f * fast_rcp(1.0f + __expf(y)); }
__device__ __forceinline__ float tanh_raw(float x) { return tanh_e(2.0f * x); }

__global__ void precompute_kernel(const float* __restrict__ Ws, const float* __restrict__ bs,
                                  const float* __restrict__ Wd, const float* __restrict__ bd,
                                  const float* __restrict__ Wdec, const float* __restrict__ bdec,
                                  const float* __restrict__ W_ih, const float* __restrict__ b_ih,
                                  const float* __restrict__ Wa, const float* __restrict__ va,
                                  const float* __restrict__ Wp, const float* __restrict__ vp,
                                  float* __restrict__ ws)
{
    int tid = blockIdx.x * blockDim.x + threadIdx.x;
    if (tid < 768) {                              // Mgi
        int j = tid; const float* wr = &W_ih[j * NH];
        float m0 = 0.f, m1 = 0.f;
        for (int k = 0; k < NH; k++) { float w = wr[k]; m0 = fmaf(w, Wdec[2*k], m0); m1 = fmaf(w, Wdec[2*k+1], m1); }
        ws[2*j] = m0; ws[2*j+1] = m1;
    } else if (tid < 1536) {                      // cgi
        int j = tid - 768; const float* wr = &W_ih[j * NH];
        float c = b_ih[j];
        for (int k = 0; k < NH; k++) c = fmaf(wr[k], bdec[k], c);
        ws[1536 + j] = c;
    } else if (tid < 1792) {                      // cA (x2 scaled except va)
        int h = tid - 1536; const float* war = &Wa[h * NH3];
        float as0 = 0.f, as1 = 0.f, ad1 = 0.f;
        for (int k = 0; k < NH; k++) {
            float w = war[k];
            as0 = fmaf(w, Ws[2*k], as0); as1 = fmaf(w, Ws[2*k+1], as1);
            ad1 = fmaf(war[NH + k], Wd[2*k+1], ad1);
        }
        float4 v = make_float4(2.f*as0, 2.f*as1, 2.f*ad1, va[h]);
        ((float4*)(ws + 2304))[h] = v;
    } else if (tid < 2048) {                      // a0 (x2)
        int h = tid - 1792; const float* war = &Wa[h * NH3];
        float a = 0.f;
        for (int k = 0; k < NH; k++) {
            a = fmaf(war[k], bs[k], a);
            a = fmaf(war[NH + k], fmaf(20.0f, Wd[2*k], bd[k]), a);
        }
        ws[3328 + h] = 2.f * a;
    } else if (tid < 2304) {                      // cP (x2 scaled except vp)
        int h = tid - 2048; const float* wpr = &Wp[h * 2 * NH];
        float p0 = 0.f, p1 = 0.f;
        for (int k = 0; k < NH; k++) { float w = wpr[k]; p0 = fmaf(w, Ws[2*k], p0); p1 = fmaf(w, Ws[2*k+1], p1); }
        float4 v = make_float4(2.f*p0, 2.f*p1, vp[h], 0.f);
        ((float4*)(ws + 3584))[h] = v;
    } else if (tid < 2560) {                      // pb = Wp_s·bs + Wp_c·bs (x2)
        int i = tid - 2304; const float* wpr = &Wp[i * 2 * NH];
        float p = 0.f;
        for (int k = 0; k < NH; k++) { p = fmaf(wpr[k], bs[k], p); p = fmaf(wpr[NH + k], bs[k], p); }
        ws[4608 + i] = 2.f * p;
    } else if (tid < 2816) {                      // PC0 (x2)
        int i = tid - 2560; const float* wpc = &Wp[i * 2 * NH + NH];
        float p = 0.f;
        for (int k = 0; k < NH; k++) p = fmaf(wpc[k], Ws[2*k], p);
        ws[4864 + i] = 2.f * p;
    } else if (tid < 3072) {                      // PC1 (x2)
        int i = tid - 2816; const float* wpc = &Wp[i * 2 * NH + NH];
        float p = 0.f;
        for (int k = 0; k < NH; k++) p = fmaf(wpc[k], Ws[2*k+1], p);
        ws[5120 + i] = 2.f * p;
    } else if (tid < 3072 + 65536) {              // WaH pack (x2)
        int m = tid - 3072; int i = m >> 8, j = m & 255;
        ws[5376 + m] = 2.f * Wa[i * NH3 + 2 * NH + j];
    }
}

__global__ void __launch_bounds__(512)
drl_main(const float* __restrict__ gstatic, const float* __restrict__ gdyn,
         const float* __restrict__ glast, const float* __restrict__ gWhh,
         const float* __restrict__ gbhh, const float* __restrict__ wsb,
         float* __restrict__ out)
{
    __shared__ float s0[2][NN], s1[2][NN], d1[2][NN];
    __shared__ float hs[2][NH];
    __shared__ float ghs[2][NH3];
    __shared__ float qp[2][NH];
    __shared__ float pcp[2][NH];
    __shared__ float scs[2][NH];
    __shared__ float4 cA[NH];
    __shared__ float4 cP[NH];
    __shared__ float2 Mgi[NH3];
    __shared__ float cgi[NH3], bhh[NH3];
    __shared__ float a0v[NH], pbv[NH], PC0v[NH], PC1v[NH];
    __shared__ float Sw[2][2];
    __shared__ int idxs[2];

    const int t = threadIdx.x;
    const int g = t >> 8;          // which of the 2 batch elements this thread serves
    const int r = t & 255;
    const int b0 = blockIdx.x * 2;

    // ---- setup: stage inputs + coefficients into LDS
    for (int i = t; i < 2 * NN; i += 512) {
        int gg = i >> 7, n = i & 127, b = b0 + gg;
        s0[gg][n] = gstatic[b * (NF * NN) + n];
        s1[gg][n] = gstatic[b * (NF * NN) + NN + n];
        d1[gg][n] = gdyn[b * (NF * NN) + NN + n];
    }
    for (int i = t; i < 2 * NH; i += 512) {
        int gg = i >> 8, j = i & 255;
        hs[gg][j] = glast[(b0 + gg) * NH + j];
    }
    for (int i = t; i < 1536; i += 512) ((float*)Mgi)[i] = wsb[i];
    for (int i = t; i < 768;  i += 512) cgi[i] = wsb[1536 + i];
    for (int i = t; i < 1024; i += 512) ((float*)cA)[i] = wsb[2304 + i];
    if (t < 256) a0v[t] = wsb[3328 + t];
    for (int i = t; i < 1024; i += 512) ((float*)cP)[i] = wsb[3584 + i];
    if (t < 256) { pbv[t] = wsb[4608 + t]; PC0v[t] = wsb[4864 + t]; PC1v[t] = wsb[5120 + t]; }
    for (int i = t; i < 768;  i += 512) bhh[i] = gbhh[i];
    if (t == 0) { idxs[0] = 0; idxs[1] = 0; }
    __syncthreads();

    const float* WaH = wsb + 5376;
    const int jb = t >> 2, kq = t & 3;   // quad-split GEMV: 128 rows/pass, 4 lanes split k

    // ---- initial gh = W_hh*last_hh + b_hh
    {
        float acc[12];
        #pragma unroll
        for (int i = 0; i < 12; i++) acc[i] = 0.f;
        const float* wb = gWhh + jb * NH + 4 * kq;
        #pragma unroll 2
        for (int c = 0; c < 16; c++) {
            float4 h0 = *(const float4*)&hs[0][16 * c + 4 * kq];
            float4 h1 = *(const float4*)&hs[1][16 * c + 4 * kq];
            #pragma unroll
            for (int p = 0; p < 6; p++) {
                float4 w = *(const float4*)(wb + p * 128 * NH + 16 * c);
                acc[2*p]   = fmaf(w.x,h0.x,fmaf(w.y,h0.y,fmaf(w.z,h0.z,fmaf(w.w,h0.w,acc[2*p]))));
                acc[2*p+1] = fmaf(w.x,h1.x,fmaf(w.y,h1.y,fmaf(w.z,h1.z,fmaf(w.w,h1.w,acc[2*p+1]))));
            }
        }
        #pragma unroll
        for (int p = 0; p < 6; p++) {
            float u0 = acc[2*p], u1 = acc[2*p+1];
            u0 += __shfl_xor(u0, 1); u0 += __shfl_xor(u0, 2);
            u1 += __shfl_xor(u1, 1); u1 += __shfl_xor(u1, 2);
            if (kq == 0) { int j = jb + 128 * p; ghs[0][j] = u0 + bhh[j]; ghs[1][j] = u1 + bhh[j]; }
        }
    }
    __syncthreads();

    for (int step = 0; step < NN; step++) {
        // ---- P2: GRU elementwise (gi collapsed via Mgi/cgi)
        {
            int id = idxs[g];
            float sv0 = s0[g][id], sv1 = s1[g][id];
            float2 m0 = Mgi[r], m1 = Mgi[NH + r], m2 = Mgi[2 * NH + r];
            float ir  = fmaf(m0.x, sv0, fmaf(m0.y, sv1, cgi[r]));
            float iz  = fmaf(m1.x, sv0, fmaf(m1.y, sv1, cgi[NH + r]));
            float inn = fmaf(m2.x, sv0, fmaf(m2.y, sv1, cgi[2 * NH + r]));
            float rr = sigm(ir + ghs[g][r]);
            float zz = sigm(iz + ghs[g][NH + r]);
            float nv = tanh_raw(fmaf(rr, ghs[g][2 * NH + r], inn));
            float ho = hs[g][r];
            hs[g][r] = fmaf(zz, ho - nv, nv);            // (1-z)n + z*h
        }
        __syncthreads();
        // ---- P3: gh(next) = W_hh*h  and  q = Wa_h*h (both batch elems share reads)
        {
            float acc[12], qa[4];
            #pragma unroll
            for (int i = 0; i < 12; i++) acc[i] = 0.f;
            #pragma unroll
            for (int i = 0; i < 4; i++) qa[i] = 0.f;
            const float* wb = gWhh + jb * NH + 4 * kq;
            const float* qb = WaH + jb * NH + 4 * kq;
            #pragma unroll 2
            for (int c = 0; c < 16; c++) {
                float4 h0 = *(const float4*)&hs[0][16 * c + 4 * kq];
                float4 h1 = *(const float4*)&hs[1][16 * c + 4 * kq];
                #pragma unroll
                for (int p = 0; p < 6; p++) {
                    float4 w = *(const float4*)(wb + p * 128 * NH + 16 * c);
                    acc[2*p]   = fmaf(w.x,h0.x,fmaf(w.y,h0.y,fmaf(w.z,h0.z,fmaf(w.w,h0.w,acc[2*p]))));
                    acc[2*p+1] = fmaf(w.x,h1.x,fmaf(w.y,h1.y,fmaf(w.z,h1.z,fmaf(w.w,h1.w,acc[2*p+1]))));
                }
                #pragma unroll
                for (int p = 0; p < 2; p++) {
                    float4 w = *(const float4*)(qb + p * 128 * NH + 16 * c);
                    qa[2*p]   = fmaf(w.x,h0.x,fmaf(w.y,h0.y,fmaf(w.z,h0.z,fmaf(w.w,h0.w,qa[2*p]))));
                    qa[2*p+1] = fmaf(w.x,h1.x,fmaf(w.y,h1.y,fmaf(w.z,h1.z,fmaf(w.w,h1.w,qa[2*p+1]))));
                }
            }
            #pragma unroll
            for (int p = 0; p < 6; p++) {
                float u0 = acc[2*p], u1 = acc[2*p+1];
                u0 += __shfl_xor(u0, 1); u0 += __shfl_xor(u0, 2);
                u1 += __shfl_xor(u1, 1); u1 += __shfl_xor(u1, 2);
                if (kq == 0) { int j = jb + 128 * p; ghs[0][j] = u0 + bhh[j]; ghs[1][j] = u1 + bhh[j]; }
            }
            #pragma unroll
            for (int p = 0; p < 2; p++) {
                float u0 = qa[2*p], u1 = qa[2*p+1];
                u0 += __shfl_xor(u0, 1); u0 += __shfl_xor(u0, 2);
                u1 += __shfl_xor(u1, 1); u1 += __shfl_xor(u1, 2);
                if (kq == 0) { int i = jb + 128 * p; qp[0][i] = u0 + a0v[i]; qp[1][i] = u1 + a0v[i]; }
            }
        }
        __syncthreads();
        // ---- P4: attention scores  u=tanh(pre_attn+q); sc = sum_h va*u (half-h per thread)
        {
            int n = r >> 1, hh = r & 1;
            float sv0 = s0[g][n], sv1 = s1[g][n], dv = d1[g][n];
            float acc = 0.f;
            int hbase = hh * 128;
            #pragma unroll 4
            for (int i = 0; i < 128; i++) {
                int hI = hbase + i;
                float4 c4 = cA[hI];
                float x = fmaf(c4.x, sv0, fmaf(c4.y, sv1, fmaf(c4.z, dv, qp[g][hI])));
                acc = fmaf(c4.w, tanh_e(x), acc);
            }
            scs[g][r] = acc;
        }
        __syncthreads();
        // ---- P5: softmax over n -> weighted sums S0w,S1w (context collapses)
        if (r < 64) {
            int l = r;
            float v0 = scs[g][2*l] + scs[g][2*l+1];
            float v1 = scs[g][128 + 2*l] + scs[g][129 + 2*l];
            float m = fmaxf(v0, v1);
            #pragma unroll
            for (int o = 32; o; o >>= 1) m = fmaxf(m, __shfl_xor(m, o));
            float e0 = __expf(v0 - m), e1 = __expf(v1 - m);
            float ss = e0 + e1;
            #pragma unroll
            for (int o = 32; o; o >>= 1) ss += __shfl_xor(ss, o);
            float rs = fast_rcp(ss);
            float w0 = e0 * rs, w1 = e1 * rs;
            float t0 = fmaf(w0, s0[g][l], w1 * s0[g][l + 64]);
            float t1 = fmaf(w0, s1[g][l], w1 * s1[g][l + 64]);
            #pragma unroll
            for (int o = 32; o; o >>= 1) { t0 += __shfl_xor(t0, o); t1 += __shfl_xor(t1, o); }
            if (l == 0) { Sw[g][0] = t0; Sw[g][1] = t1; }
        }
        __syncthreads();
        // ---- P6: pointer bias pcp = Wp_c*context + p0 (collapsed)
        pcp[g][r] = fmaf(PC0v[r], Sw[g][0], fmaf(PC1v[r], Sw[g][1], pbv[r]));
        __syncthreads();
        // ---- P7: pointer scores e=tanh(pre_ptr+pc); sp = sum_h vp*e
        {
            int n = r >> 1, hh = r & 1;
            float sv0 = s0[g][n], sv1 = s1[g][n];
            float acc = 0.f;
            int hbase = hh * 128;
            #pragma unroll 4
            for (int i = 0; i < 128; i++) {
                int hI = hbase + i;
                float4 c4 = cP[hI];
                float x = fmaf(c4.x, sv0, fmaf(c4.y, sv1, pcp[g][hI]));
                acc = fmaf(c4.z, tanh_e(x), acc);
            }
            scs[g][r] = acc;
        }
        __syncthreads();
        // ---- P8: softmax2 + argmax (first-index tiebreak) + outputs
        if (r < 64) {
            int l = r;
            float v0 = scs[g][2*l] + scs[g][2*l+1];
            float v1 = scs[g][128 + 2*l] + scs[g][129 + 2*l];
            float bv = v0; int bi = l;
            if (v1 > v0) { bv = v1; bi = l + 64; }
            #pragma unroll
            for (int o = 32; o; o >>= 1) {
                float ov = __shfl_xor(bv, o); int oi = __shfl_xor(bi, o);
                if (ov > bv || (ov == bv && oi < bi)) { bv = ov; bi = oi; }
            }
            float e0 = __expf(v0 - bv), e1 = __expf(v1 - bv);
            float ss = e0 + e1;
            #pragma unroll
            for (int o = 32; o; o >>= 1) ss += __shfl_xor(ss, o);
            if (l == 0) {
                idxs[g] = bi;
                int b = b0 + g;
                out[b * NN + step] = (float)bi;                 // tour_idx (B,N), as f32
                out[NB * NN + b * NN + step] = -logf(ss);       // tour_logp (B,N)
            }
        }
        __syncthreads();
    }
}

extern "C" void kernel_launch(void* const* d_in, const int* in_sizes, int n_in,
                              void* d_out, int out_size, void* d_ws, size_t ws_size,
                              hipStream_t stream) {
    const float* gstatic = (const float*)d_in[0];
    const float* gdyn    = (const float*)d_in[1];
    const float* glast   = (const float*)d_in[2];
    const float* Ws      = (const float*)d_in[3];
    const float* bs      = (const float*)d_in[4];
    const float* Wd      = (const float*)d_in[5];
    const float* bd      = (const float*)d_in[6];
    const float* Wdec    = (const float*)d_in[7];
    const float* bdec    = (const float*)d_in[8];
    const float* W_ih    = (const float*)d_in[9];
    const float* W_hh    = (const float*)d_in[10];
    const float* b_ih    = (const float*)d_in[11];
    const float* b_hh    = (const float*)d_in[12];
    const float* Wa      = (const float*)d_in[13];
    const float* va      = (const float*)d_in[14];
    const float* Wp      = (const float*)d_in[15];
    const float* vp      = (const float*)d_in[16];
    float* outp = (float*)d_out;
    float* wsb  = (float*)d_ws;

    // 3072 coefficient dots + 65536 WaH pack = 68608 tasks = 268 * 256
    precompute_kernel<<<268, 256, 0, stream>>>(Ws, bs, Wd, bd, Wdec, bdec,
                                               W_ih, b_ih, Wa, va, Wp, vp, wsb);
    drl_main<<<256, 512, 0, stream>>>(gstatic, gdyn, glast, W_hh, b_hh, wsb, outp);
}